// Round 4
// baseline (1387.695 us; speedup 1.0000x reference)
//
#include <hip/hip_runtime.h>
#include <cstdint>
#include <cstddef>

// ---------- types ----------
typedef __attribute__((ext_vector_type(8))) __bf16 bf16x8;
typedef __attribute__((ext_vector_type(4))) float f32x4;
typedef __attribute__((ext_vector_type(4))) unsigned short u16x4;

#define NBLK 256

__device__ __forceinline__ unsigned short f2bf(float f) {
  unsigned int u = __builtin_bit_cast(unsigned int, f);
  u += 0x7fffu + ((u >> 16) & 1u);           // RNE
  return (unsigned short)(u >> 16);
}
__device__ __forceinline__ float bf2f(unsigned short u) {
  return __builtin_bit_cast(float, ((unsigned int)u) << 16);
}

// ---------- device-scope grid barrier (sense via monotonically increasing epoch) ----------
__device__ __forceinline__ void gbar(unsigned* cnt, unsigned* flag, unsigned& lep) {
  __syncthreads();
  unsigned e = ++lep;
  if (threadIdx.x == 0) {
    __threadfence();   // writeback this XCD's L2 (release side for our data)
    unsigned prev = __hip_atomic_fetch_add(cnt, 1u, __ATOMIC_ACQ_REL, __HIP_MEMORY_SCOPE_AGENT);
    if (prev == (unsigned)(NBLK - 1)) {
      __hip_atomic_store(cnt, 0u, __ATOMIC_RELAXED, __HIP_MEMORY_SCOPE_AGENT);
      __hip_atomic_store(flag, e, __ATOMIC_RELEASE, __HIP_MEMORY_SCOPE_AGENT);
    } else {
      long long guard = 0;
      while (__hip_atomic_load(flag, __ATOMIC_RELAXED, __HIP_MEMORY_SCOPE_AGENT) < e) {
        __builtin_amdgcn_s_sleep(8);
        if (++guard > (1LL << 22)) break;   // emergency bail — never expected
      }
    }
    __threadfence();   // invalidate L1/L2 (acquire side for others' data)
  }
  __syncthreads();
}

// ---------- GEMM pieces (proven in R1-R3) ----------
template <int ITERS>
__device__ __forceinline__ void stage_tile(const unsigned short* __restrict__ g, int ld,
                                           int k0, char* lbase, int tid) {
#pragma unroll
  for (int it = 0; it < ITERS; ++it) {
    int c = tid + it * 256;              // 16B chunk id; 8 chunks per 64-k row
    int r = c >> 3;
    int c8 = (c & 7) ^ (r & 7);          // pre-swizzled global source (m173 pattern)
    const unsigned short* src = g + (size_t)r * ld + (k0 + c8 * 8);
    char* dst = lbase + c * 16;          // linear LDS dest
    __builtin_amdgcn_global_load_lds((__attribute__((address_space(1))) void*)src,
                                     (__attribute__((address_space(3))) void*)dst, 16, 0, 0);
  }
}

__device__ __forceinline__ bf16x8 ld_frag(const char* base, int row, int k8) {
  int off = (row << 7) + ((k8 ^ (row & 7)) << 4);   // XOR swizzle (G4)
  return *(const bf16x8*)(base + off);
}

// TM=128. TN=64: wave owns 32x64 (MR=2). TN=128: wave owns 64x64 (MR=4).
// OMODE: 0=f32 out, 1=bf16 out, 2=both.
template <int TN, int ACT, int OMODE, bool RES>
__device__ void gemm_tile(char* smem,
    const unsigned short* __restrict__ A, int lda,
    const unsigned short* __restrict__ BT, int ldb, int Kloop,
    const float* __restrict__ bias, const float* __restrict__ res,
    float* __restrict__ outF, unsigned short* __restrict__ outB,
    int ldC, int Nstore, int m0, int n0, int koff) {
  constexpr int MR = (TN == 64) ? 2 : 4;
  constexpr int BUFS = 16384 + TN * 128;   // A 16KB + B per buffer
  const int tid = threadIdx.x;
  const int lane = tid & 63;
  const int wid = tid >> 6;
  const int rowbase = (TN == 64) ? wid * 32 : (wid >> 1) * 64;
  const int colbase = (TN == 64) ? 0 : (wid & 1) * 64;
  const unsigned short* Ag = A + (size_t)m0 * lda + koff;
  const unsigned short* Bg = BT + (size_t)n0 * ldb + koff;
  f32x4 acc[MR][4];
#pragma unroll
  for (int m = 0; m < MR; m++)
#pragma unroll
    for (int n = 0; n < 4; n++) acc[m][n] = 0.f;
  const int nt = Kloop >> 6;
  stage_tile<4>(Ag, lda, 0, smem, tid);
  stage_tile<TN / 32>(Bg, ldb, 0, smem + 16384, tid);
  __syncthreads();
  int cur = 0;
  const int rA = lane & 15, kq = lane >> 4;
  for (int t = 0; t < nt; ++t) {
    if (t + 1 < nt) {
      stage_tile<4>(Ag, lda, (t + 1) << 6, smem + (cur ^ 1) * BUFS, tid);
      stage_tile<TN / 32>(Bg, ldb, (t + 1) << 6, smem + (cur ^ 1) * BUFS + 16384, tid);
    }
    const char* la = smem + cur * BUFS;
    const char* lb = la + 16384;
#pragma unroll
    for (int kk = 0; kk < 2; ++kk) {
      int k8 = kk * 4 + kq;
      bf16x8 af[MR], bfr[4];
#pragma unroll
      for (int m = 0; m < MR; m++) af[m] = ld_frag(la, rowbase + m * 16 + rA, k8);
#pragma unroll
      for (int n = 0; n < 4; n++) bfr[n] = ld_frag(lb, colbase + n * 16 + rA, k8);
#pragma unroll
      for (int m = 0; m < MR; m++)
#pragma unroll
        for (int n = 0; n < 4; n++)
          acc[m][n] = __builtin_amdgcn_mfma_f32_16x16x32_bf16(af[m], bfr[n], acc[m][n], 0, 0, 0);
    }
    __syncthreads();
    cur ^= 1;
  }
  const int rb = m0 + rowbase + (kq << 2);
  const int cb = n0 + colbase + rA;
#pragma unroll
  for (int m = 0; m < MR; m++)
#pragma unroll
    for (int n = 0; n < 4; n++) {
      int cg = cb + n * 16;
      if (cg >= Nstore) continue;
      float bv = bias ? bias[cg] : 0.0f;
#pragma unroll
      for (int j = 0; j < 4; j++) {
        int rg = rb + m * 16 + j;
        float v = acc[m][n][j] + bv;
        if (RES) v += res[(size_t)rg * ldC + cg];
        if (ACT == 1) v = 0.5f * v * (1.0f + erff(v * 0.70710678118654752f));
        if (OMODE == 0) {
          outF[(size_t)rg * ldC + cg] = v;
        } else if (OMODE == 1) {
          outB[(size_t)rg * ldC + cg] = f2bf(v);
        } else {
          outF[(size_t)rg * ldC + cg] = v;
          outB[(size_t)rg * ldC + cg] = f2bf(v);
        }
      }
    }
}

// ---------- weight cast+transpose, one 64x64 tile ----------
__device__ void wcast_tile(char* smemc, int bid,
    const float* s_img, const float* s_qkv, const float* s_o,
    const float* s_ff1, const float* s_ff2, const float* s_cls,
    unsigned short* d_img, unsigned short* d_qkv, unsigned short* d_o,
    unsigned short* d_ff1, unsigned short* d_ff2, unsigned short* d_cls) {
  float (*tile)[65] = (float (*)[65])smemc;
  const float* src; unsigned short* dst; int K, N, Npad, rel;
  if (bid < 1024)       { src = s_img; dst = d_img; K = 4096; N = 1024; Npad = 1024; rel = bid; }
  else if (bid < 2560)  { rel = bid - 1024; int l = rel / 384; rel -= l * 384;
                          src = s_qkv + (size_t)l * 1024 * 1536; dst = d_qkv + (size_t)l * 1536 * 1024;
                          K = 1024; N = 1536; Npad = 1536; }
  else if (bid < 3072)  { rel = bid - 2560; int l = rel / 128; rel -= l * 128;
                          src = s_o   + (size_t)l * 512 * 1024;  dst = d_o   + (size_t)l * 1024 * 512;
                          K = 512;  N = 1024; Npad = 1024; }
  else if (bid < 4096)  { rel = bid - 3072; int l = rel / 256; rel -= l * 256;
                          src = s_ff1 + (size_t)l * 1024 * 1024; dst = d_ff1 + (size_t)l * 1024 * 1024;
                          K = 1024; N = 1024; Npad = 1024; }
  else if (bid < 5120)  { rel = bid - 4096; int l = rel / 256; rel -= l * 256;
                          src = s_ff2 + (size_t)l * 1024 * 1024; dst = d_ff2 + (size_t)l * 1024 * 1024;
                          K = 1024; N = 1024; Npad = 1024; }
  else                  { rel = bid - 5120; src = s_cls; dst = d_cls; K = 8192; N = 1000; Npad = 1024; }
  int tilesX = Npad >> 6;
  int nx = rel % tilesX, ky = rel / tilesX;
  int n0 = nx << 6, k0 = ky << 6;
  int t = threadIdx.x;
#pragma unroll
  for (int i = 0; i < 4; ++i) {
    int slot = t + i * 256;
    int kk = slot >> 4, cq = slot & 15;
    int n = n0 + cq * 4;
    float4 v;
    if (n + 3 < N) v = *(const float4*)(src + (size_t)(k0 + kk) * N + n);
    else {
      v.x = v.y = v.z = v.w = 0.0f;
      if (n < N)     v.x = src[(size_t)(k0 + kk) * N + n];
      if (n + 1 < N) v.y = src[(size_t)(k0 + kk) * N + n + 1];
      if (n + 2 < N) v.z = src[(size_t)(k0 + kk) * N + n + 2];
      if (n + 3 < N) v.w = src[(size_t)(k0 + kk) * N + n + 3];
    }
    tile[kk][cq * 4 + 0] = v.x;
    tile[kk][cq * 4 + 1] = v.y;
    tile[kk][cq * 4 + 2] = v.z;
    tile[kk][cq * 4 + 3] = v.w;
  }
  __syncthreads();
#pragma unroll
  for (int i = 0; i < 4; ++i) {
    int slot = t + i * 256;
    int n = slot >> 4, kq = slot & 15;
    u16x4 o;
    o.x = f2bf(tile[kq * 4 + 0][n]);
    o.y = f2bf(tile[kq * 4 + 1][n]);
    o.z = f2bf(tile[kq * 4 + 2][n]);
    o.w = f2bf(tile[kq * 4 + 3][n]);
    *(u16x4*)(dst + (size_t)(n0 + n) * K + k0 + kq * 4) = o;
  }
  __syncthreads();
}

// ---------- LayerNorm one row (wave-level) ----------
__device__ __forceinline__ void ln_row(const float* __restrict__ z, int row,
                                       const float* __restrict__ sc, const float* __restrict__ bi,
                                       unsigned short* __restrict__ h) {
  int lane = threadIdx.x & 63;
  const float* zr = z + (size_t)row * 1024;
  float4 v[4];
  float s = 0.f, q = 0.f;
#pragma unroll
  for (int i = 0; i < 4; i++) {
    v[i] = *(const float4*)(zr + lane * 4 + i * 256);
    s += v[i].x + v[i].y + v[i].z + v[i].w;
    q += v[i].x * v[i].x + v[i].y * v[i].y + v[i].z * v[i].z + v[i].w * v[i].w;
  }
#pragma unroll
  for (int off = 32; off; off >>= 1) { s += __shfl_xor(s, off); q += __shfl_xor(q, off); }
  float mean = s * (1.0f / 1024.0f);
  float var = q * (1.0f / 1024.0f) - mean * mean;
  float rstd = rsqrtf(var + 1e-5f);
  u16x4* out = (u16x4*)(h + (size_t)row * 1024);
#pragma unroll
  for (int i = 0; i < 4; i++) {
    int c = lane * 4 + i * 256;
    float4 sv = *(const float4*)(sc + c);
    float4 bv = *(const float4*)(bi + c);
    u16x4 o;
    o.x = f2bf((v[i].x - mean) * rstd * sv.x + bv.x);
    o.y = f2bf((v[i].y - mean) * rstd * sv.y + bv.y);
    o.z = f2bf((v[i].z - mean) * rstd * sv.z + bv.z);
    o.w = f2bf((v[i].w - mean) * rstd * sv.w + bv.w);
    out[lane + i * 64] = o;
  }
}

// ---------- the megakernel ----------
__global__ __launch_bounds__(256) void mega(
    const float* __restrict__ x, const float* __restrict__ tr, const float* __restrict__ hist,
    const float* __restrict__ w_img, const float* __restrict__ b_img,
    const float* __restrict__ ln1_s, const float* __restrict__ ln1_b,
    const float* __restrict__ w_qkv,
    const float* __restrict__ w_o, const float* __restrict__ b_o,
    const float* __restrict__ ln2_s, const float* __restrict__ ln2_b,
    const float* __restrict__ w_ff1, const float* __restrict__ b_ff1,
    const float* __restrict__ w_ff2, const float* __restrict__ b_ff2,
    const float* __restrict__ w_cls, const float* __restrict__ b_cls,
    const float* __restrict__ w_tr, const float* __restrict__ b_tr,
    unsigned short* BT_img, unsigned short* BT_qkv, unsigned short* BT_o,
    unsigned short* BT_ff1, unsigned short* BT_ff2, unsigned short* BT_cls,
    unsigned short* feats, float* z, unsigned short* h, unsigned short* qkvb,
    unsigned short* obuf, unsigned short* g, float* part,
    float* outF, unsigned* bar) {
  __shared__ __align__(16) char smem[65536];
  const int bid = blockIdx.x;
  const int tid = threadIdx.x;
  const int lane = tid & 63;
  const int wid = tid >> 6;
  unsigned* cnt = bar;
  unsigned* flag = bar + 16;   // separate cache lines
  unsigned lep = 0;

  // ---- P0: weight prep + crop + zinit (independent) ----
  for (int wt = bid; wt < 7168; wt += NBLK)
    wcast_tile(smem, wt, w_img, w_qkv, w_o, w_ff1, w_ff2, w_cls,
               BT_img, BT_qkv, BT_o, BT_ff1, BT_ff2, BT_cls);
  {
    // crop: batch = bid
    int* xi = (int*)smem;
    int* yi = xi + 64;
    int b = bid;
    float px = tr[b * 4 + 0], py = tr[b * 4 + 1], zx = tr[b * 4 + 2], zy = tr[b * 4 + 3];
    float x1 = __fmul_rn(px, 448.0f);
    float y1 = __fmul_rn(py, 448.0f);
    float xs = fminf(__fsub_rn(512.0f, x1), __fadd_rn(__fmul_rn(zx, 448.0f), 64.0f));
    float ys = fminf(__fsub_rn(512.0f, y1), __fadd_rn(__fmul_rn(zy, 448.0f), 64.0f));
    if (tid < 64) {
      float u = __fmul_rn(__fmul_rn((float)tid, 0.015625f), xs);
      int v = (int)(__fadd_rn(floorf(u), x1));
      xi[tid] = min(max(v, 0), 511);
    } else if (tid < 128) {
      int tt = tid - 64;
      float u = __fmul_rn(__fmul_rn((float)tt, 0.015625f), ys);
      int v = (int)(__fadd_rn(floorf(u), y1));
      yi[tt] = min(max(v, 0), 511);
    }
    __syncthreads();
    const float* img = x + (size_t)b * 262144;
    for (int p = tid; p < 4096; p += 256) {
      int i = p >> 6, j = p & 63;
      float val = img[xi[i] * 512 + yi[j]] * 128.0f;
      feats[(size_t)b * 4096 + p] = f2bf(val);
    }
    __syncthreads();
  }
  for (int idx = bid * 256 + tid; idx < 458752; idx += NBLK * 256) {
    int off = idx * 4;
    int b = off / 7168;
    int r = off - b * 7168;
    int i = r >> 10, c = r & 1023;
    float4 v = *(const float4*)(hist + (size_t)(i + 1) * 262144 + (size_t)b * 1024 + c);
    *(float4*)(z + (size_t)b * 8192 + i * 1024 + c) = v;
  }
  gbar(cnt, flag, lep);   // 1

  // ---- P1: image-latent GEMM, split-K x8 (Kc=512), 256 tiles exactly ----
  {
    int sk = bid >> 5, r = bid & 31, my = r >> 4, nx = r & 15;
    gemm_tile<64, 0, 0, false>(smem, feats, 4096, BT_img, 4096, 512,
                               nullptr, nullptr, part + (size_t)sk * 262144, nullptr,
                               1024, 1024, my * 128, nx * 64, sk * 512);
  }
  gbar(cnt, flag, lep);   // 2

  // ---- P2: img reduce -> z[:,7,:] ----
  {
    int m = bid, c = tid * 4;
    float4 a = {0.f, 0.f, 0.f, 0.f};
    for (int p = 0; p < 8; ++p) {
      float4 v = *(const float4*)(part + (size_t)p * 262144 + m * 1024 + c);
      a.x += v.x; a.y += v.y; a.z += v.z; a.w += v.w;
    }
    float4 bv = *(const float4*)(b_img + c);
    a.x += bv.x; a.y += bv.y; a.z += bv.z; a.w += bv.w;
    *(float4*)(z + (size_t)m * 8192 + 7168 + c) = a;
  }
  gbar(cnt, flag, lep);   // 3

  // ---- 4 transformer layers ----
  for (int i = 0; i < 4; ++i) {
    const unsigned short* Wq = BT_qkv + (size_t)i * 1536 * 1024;
    const unsigned short* Wo = BT_o   + (size_t)i * 1024 * 512;
    const unsigned short* W1 = BT_ff1 + (size_t)i * 1024 * 1024;
    const unsigned short* W2 = BT_ff2 + (size_t)i * 1024 * 1024;

    // ln1: 8 rows per block
#pragma unroll
    for (int rr = 0; rr < 2; ++rr)
      ln_row(z, bid * 8 + wid * 2 + rr, ln1_s + i * 1024, ln1_b + i * 1024, h);
    gbar(cnt, flag, lep);

    // qkv GEMM: 16x12 tiles of 128x128
    if (bid < 192) {
      int my = bid / 12, nx = bid - my * 12;
      gemm_tile<128, 0, 1, false>(smem, h, 1024, Wq, 1024, 1024,
                                  nullptr, nullptr, nullptr, qkvb,
                                  1536, 1536, my * 128, nx * 128, 0);
    }
    gbar(cnt, flag, lep);

    // attention: 8 (b,head) pairs per block, 2 per wave
    for (int p = 0; p < 2; ++p) {
      int pair = bid * 8 + wid * 2 + p;
      int b = pair >> 3, hh = pair & 7;
      float* slab = (float*)(smem + wid * 8192);
      float* Q = slab; float* Kk = slab + 512; float* V = slab + 1024;
      float* S = slab + 1536; float* P = slab + 1600;
      const unsigned short* base = qkvb + (size_t)b * 12288 + hh * 64;
#pragma unroll
      for (int ii = 0; ii < 8; ii++) {
        Q[ii * 64 + lane]  = bf2f(base[ii * 1536 + lane]);
        Kk[ii * 64 + lane] = bf2f(base[ii * 1536 + 512 + lane]);
        V[ii * 64 + lane]  = bf2f(base[ii * 1536 + 1024 + lane]);
      }
      __syncthreads();
      {
        int ii = lane >> 3, jj = lane & 7;
        float s = 0.f;
#pragma unroll
        for (int d = 0; d < 64; d++) s += Q[ii * 64 + d] * Kk[jj * 64 + d];
        S[ii * 8 + jj] = s * 0.125f;
      }
      __syncthreads();
      {
        int ii = lane >> 3, jj = lane & 7;
        float m = S[ii * 8 + 0];
#pragma unroll
        for (int k2 = 1; k2 < 8; k2++) m = fmaxf(m, S[ii * 8 + k2]);
        float sum = 0.f;
#pragma unroll
        for (int k2 = 0; k2 < 8; k2++) sum += expf(S[ii * 8 + k2] - m);
        P[ii * 8 + jj] = expf(S[ii * 8 + jj] - m) / sum;
      }
      __syncthreads();
#pragma unroll
      for (int ii = 0; ii < 8; ii++) {
        float o = 0.f;
#pragma unroll
        for (int jj = 0; jj < 8; jj++) o += P[ii * 8 + jj] * V[jj * 64 + lane];
        obuf[(size_t)(b * 8 + ii) * 512 + hh * 64 + lane] = f2bf(o);
      }
      __syncthreads();
    }
    gbar(cnt, flag, lep);

    // proj: 16x16 tiles of 128x64, +bias +residual -> z
    {
      int my = bid >> 4, nx = bid & 15;
      gemm_tile<64, 0, 0, true>(smem, obuf, 512, Wo, 512, 512,
                                b_o + i * 1024, z, z, nullptr,
                                1024, 1024, my * 128, nx * 64, 0);
    }
    gbar(cnt, flag, lep);

    // ln2
#pragma unroll
    for (int rr = 0; rr < 2; ++rr)
      ln_row(z, bid * 8 + wid * 2 + rr, ln2_s + i * 1024, ln2_b + i * 1024, h);
    gbar(cnt, flag, lep);

    // ff1 + GELU -> g (bf16)
    {
      int my = bid >> 4, nx = bid & 15;
      gemm_tile<64, 1, 1, false>(smem, h, 1024, W1, 1024, 1024,
                                 b_ff1 + i * 1024, nullptr, nullptr, g,
                                 1024, 1024, my * 128, nx * 64, 0);
    }
    gbar(cnt, flag, lep);

    // ff2 + residual -> z (and tl bf16 on last layer)
    {
      int my = bid >> 4, nx = bid & 15;
      if (i < 3)
        gemm_tile<64, 0, 0, true>(smem, g, 1024, W2, 1024, 1024,
                                  b_ff2 + i * 1024, z, z, nullptr,
                                  1024, 1024, my * 128, nx * 64, 0);
      else
        gemm_tile<64, 0, 2, true>(smem, g, 1024, W2, 1024, 1024,
                                  b_ff2 + i * 1024, z, z, h,
                                  1024, 1024, my * 128, nx * 64, 0);
    }
    gbar(cnt, flag, lep);
  }

  // ---- cls GEMM: split-K x8 (Kc=1024), 256 tiles exactly ----
  {
    int sk = bid >> 5, r = bid & 31, my = r >> 4, nx = r & 15;
    gemm_tile<64, 0, 0, false>(smem, h, 8192, BT_cls, 8192, 1024,
                               nullptr, nullptr, part + (size_t)sk * 262144, nullptr,
                               1024, 1024, my * 128, nx * 64, sk * 1024);
  }
  gbar(cnt, flag, lep);

  // ---- final: cls reduce + transform head (block = batch row) ----
  {
    int m = bid, c = tid * 4;
    float4 a = {0.f, 0.f, 0.f, 0.f};
    for (int p = 0; p < 8; ++p) {
      float4 v = *(const float4*)(part + (size_t)p * 262144 + m * 1024 + c);
      a.x += v.x; a.y += v.y; a.z += v.z; a.w += v.w;
    }
    if (c < 1000) {
      float vals[4] = {a.x, a.y, a.z, a.w};
      float* drow = outF + (size_t)m * 1000;
      if (c + 3 < 1000) {
        *(float4*)(drow + c) = make_float4(vals[0] + b_cls[c], vals[1] + b_cls[c + 1],
                                           vals[2] + b_cls[c + 2], vals[3] + b_cls[c + 3]);
      } else {
        for (int j2 = 0; j2 < 4 && c + j2 < 1000; ++j2) drow[c + j2] = vals[j2] + b_cls[c + j2];
      }
    }
    // transform head for batch m
    const float* row = z + (size_t)m * 8192;
    float a0 = 0.f, a1 = 0.f, a2 = 0.f, a3 = 0.f;
    for (int k = tid; k < 8192; k += 256) {
      float xv = row[k];
      const float* wr = w_tr + (size_t)k * 4;
      a0 += xv * wr[0]; a1 += xv * wr[1]; a2 += xv * wr[2]; a3 += xv * wr[3];
    }
    float (*red)[4] = (float (*)[4])smem;
    __syncthreads();
    red[tid][0] = a0; red[tid][1] = a1; red[tid][2] = a2; red[tid][3] = a3;
    __syncthreads();
    for (int s = 128; s > 0; s >>= 1) {
      if (tid < s) {
#pragma unroll
        for (int o = 0; o < 4; o++) red[tid][o] += red[tid + s][o];
      }
      __syncthreads();
    }
    if (tid < 4) {
      float v = red[0][tid] + b_tr[tid];
      outF[256000 + m * 4 + tid] = 1.0f / (1.0f + expf(-v));
    }
  }
}

// ---------- barrier state init ----------
__global__ void bar_init(unsigned* b) {
  if (threadIdx.x < 32) b[threadIdx.x] = 0;
}

// ---------- launch ----------
extern "C" void kernel_launch(void* const* d_in, const int* in_sizes, int n_in,
                              void* d_out, int out_size, void* d_ws, size_t ws_size,
                              hipStream_t stream) {
  const float* x      = (const float*)d_in[0];
  const float* tr     = (const float*)d_in[1];
  const float* hist   = (const float*)d_in[2];
  const float* w_img  = (const float*)d_in[3];
  const float* b_img  = (const float*)d_in[4];
  const float* ln1_s  = (const float*)d_in[5];
  const float* ln1_b  = (const float*)d_in[6];
  const float* w_qkv  = (const float*)d_in[7];
  const float* w_o    = (const float*)d_in[8];
  const float* b_o    = (const float*)d_in[9];
  const float* ln2_s  = (const float*)d_in[10];
  const float* ln2_b  = (const float*)d_in[11];
  const float* w_ff1  = (const float*)d_in[12];
  const float* b_ff1  = (const float*)d_in[13];
  const float* w_ff2  = (const float*)d_in[14];
  const float* b_ff2  = (const float*)d_in[15];
  const float* w_cls  = (const float*)d_in[16];
  const float* b_cls  = (const float*)d_in[17];
  const float* w_tr   = (const float*)d_in[18];
  const float* b_tr   = (const float*)d_in[19];
  float* outF = (float*)d_out;

  char* w = (char*)d_ws;
  auto alloc = [&](size_t bytes) { char* p = w; w += (bytes + 255) & ~(size_t)255; return p; };
  unsigned short* BT_img = (unsigned short*)alloc((size_t)1024 * 4096 * 2);
  unsigned short* BT_qkv = (unsigned short*)alloc((size_t)4 * 1536 * 1024 * 2);
  unsigned short* BT_o   = (unsigned short*)alloc((size_t)4 * 1024 * 512 * 2);
  unsigned short* BT_ff1 = (unsigned short*)alloc((size_t)4 * 1024 * 1024 * 2);
  unsigned short* BT_ff2 = (unsigned short*)alloc((size_t)4 * 1024 * 1024 * 2);
  unsigned short* BT_cls = (unsigned short*)alloc((size_t)1024 * 8192 * 2);
  unsigned short* feats  = (unsigned short*)alloc((size_t)256 * 4096 * 2);
  float*          z      = (float*)alloc((size_t)2048 * 1024 * 4);
  unsigned short* h      = (unsigned short*)alloc((size_t)2048 * 1024 * 2);  // also tl
  unsigned short* qkvb   = (unsigned short*)alloc((size_t)2048 * 1536 * 2);
  unsigned short* obuf   = (unsigned short*)alloc((size_t)2048 * 512 * 2);
  unsigned short* g      = (unsigned short*)alloc((size_t)2048 * 1024 * 2);
  float*          part   = (float*)alloc((size_t)8 * 256 * 1024 * 4);
  unsigned*       bar    = (unsigned*)alloc(256);
  if ((size_t)(w - (char*)d_ws) > ws_size) return;

  bar_init<<<1, 64, 0, stream>>>(bar);
  mega<<<NBLK, 256, 0, stream>>>(x, tr, hist, w_img, b_img, ln1_s, ln1_b, w_qkv,
                                 w_o, b_o, ln2_s, ln2_b, w_ff1, b_ff1, w_ff2, b_ff2,
                                 w_cls, b_cls, w_tr, b_tr,
                                 BT_img, BT_qkv, BT_o, BT_ff1, BT_ff2, BT_cls,
                                 feats, z, h, qkvb, obuf, g, part, outF, bar);
}

// Round 5
// 376.945 us; speedup vs baseline: 3.6814x; 3.6814x over previous
//
#include <hip/hip_runtime.h>
#include <cstdint>
#include <cstddef>

// ---------- types ----------
typedef __attribute__((ext_vector_type(8))) __bf16 bf16x8;
typedef __attribute__((ext_vector_type(4))) float f32x4;
typedef __attribute__((ext_vector_type(4))) unsigned short u16x4;

__device__ __forceinline__ unsigned short f2bf(float f) {
  unsigned int u = __builtin_bit_cast(unsigned int, f);
  u += 0x7fffu + ((u >> 16) & 1u);           // RNE
  return (unsigned short)(u >> 16);
}
__device__ __forceinline__ float bf2f(unsigned short u) {
  return __builtin_bit_cast(float, ((unsigned int)u) << 16);
}

// ---------- weight cast+transpose, one 64x64 tile (tile id in [0,7168)) ----------
// id ranges: img [0,1024) qkv [1024,2560) o [2560,3072) ff1 [3072,4096)
//            ff2 [4096,5120) cls [5120,7168)
__device__ void wcast_tile(char* smemc, int bid,
    const float* s_img, const float* s_qkv, const float* s_o,
    const float* s_ff1, const float* s_ff2, const float* s_cls,
    unsigned short* d_img, unsigned short* d_qkv, unsigned short* d_o,
    unsigned short* d_ff1, unsigned short* d_ff2, unsigned short* d_cls) {
  float (*tile)[65] = (float (*)[65])smemc;
  const float* src; unsigned short* dst; int K, N, Npad, rel;
  if (bid < 1024)       { src = s_img; dst = d_img; K = 4096; N = 1024; Npad = 1024; rel = bid; }
  else if (bid < 2560)  { rel = bid - 1024; int l = rel / 384; rel -= l * 384;
                          src = s_qkv + (size_t)l * 1024 * 1536; dst = d_qkv + (size_t)l * 1536 * 1024;
                          K = 1024; N = 1536; Npad = 1536; }
  else if (bid < 3072)  { rel = bid - 2560; int l = rel / 128; rel -= l * 128;
                          src = s_o   + (size_t)l * 512 * 1024;  dst = d_o   + (size_t)l * 1024 * 512;
                          K = 512;  N = 1024; Npad = 1024; }
  else if (bid < 4096)  { rel = bid - 3072; int l = rel / 256; rel -= l * 256;
                          src = s_ff1 + (size_t)l * 1024 * 1024; dst = d_ff1 + (size_t)l * 1024 * 1024;
                          K = 1024; N = 1024; Npad = 1024; }
  else if (bid < 5120)  { rel = bid - 4096; int l = rel / 256; rel -= l * 256;
                          src = s_ff2 + (size_t)l * 1024 * 1024; dst = d_ff2 + (size_t)l * 1024 * 1024;
                          K = 1024; N = 1024; Npad = 1024; }
  else                  { rel = bid - 5120; src = s_cls; dst = d_cls; K = 8192; N = 1000; Npad = 1024; }
  int tilesX = Npad >> 6;
  int nx = rel % tilesX, ky = rel / tilesX;
  int n0 = nx << 6, k0 = ky << 6;
  int t = threadIdx.x;
#pragma unroll
  for (int i = 0; i < 4; ++i) {
    int slot = t + i * 256;
    int kk = slot >> 4, cq = slot & 15;
    int n = n0 + cq * 4;
    float4 v;
    if (n + 3 < N) v = *(const float4*)(src + (size_t)(k0 + kk) * N + n);
    else {
      v.x = v.y = v.z = v.w = 0.0f;
      if (n < N)     v.x = src[(size_t)(k0 + kk) * N + n];
      if (n + 1 < N) v.y = src[(size_t)(k0 + kk) * N + n + 1];
      if (n + 2 < N) v.z = src[(size_t)(k0 + kk) * N + n + 2];
      if (n + 3 < N) v.w = src[(size_t)(k0 + kk) * N + n + 3];
    }
    tile[kk][cq * 4 + 0] = v.x;
    tile[kk][cq * 4 + 1] = v.y;
    tile[kk][cq * 4 + 2] = v.z;
    tile[kk][cq * 4 + 3] = v.w;
  }
  __syncthreads();
#pragma unroll
  for (int i = 0; i < 4; ++i) {
    int slot = t + i * 256;
    int n = slot >> 4, kq = slot & 15;
    u16x4 o;
    o.x = f2bf(tile[kq * 4 + 0][n]);
    o.y = f2bf(tile[kq * 4 + 1][n]);
    o.z = f2bf(tile[kq * 4 + 2][n]);
    o.w = f2bf(tile[kq * 4 + 3][n]);
    *(u16x4*)(dst + (size_t)(n0 + n) * K + k0 + kq * 4) = o;
  }
}

// ---------- GEMM pieces (proven R1-R4) ----------
template <int ITERS>
__device__ __forceinline__ void stage_tile(const unsigned short* __restrict__ g, int ld,
                                           int k0, char* lbase, int tid) {
#pragma unroll
  for (int it = 0; it < ITERS; ++it) {
    int c = tid + it * 256;              // 16B chunk id; 8 chunks per 64-k row
    int r = c >> 3;
    int c8 = (c & 7) ^ (r & 7);          // pre-swizzled global source (m173 pattern)
    const unsigned short* src = g + (size_t)r * ld + (k0 + c8 * 8);
    char* dst = lbase + c * 16;          // linear LDS dest
    __builtin_amdgcn_global_load_lds((__attribute__((address_space(1))) void*)src,
                                     (__attribute__((address_space(3))) void*)dst, 16, 0, 0);
  }
}

__device__ __forceinline__ bf16x8 ld_frag(const char* base, int row, int k8) {
  int off = (row << 7) + ((k8 ^ (row & 7)) << 4);   // XOR swizzle (G4)
  return *(const bf16x8*)(base + off);
}

// TM=128. TN=64: wave owns 32x64 (MR=2). TN=128: wave owns 64x64 (MR=4).
// OMODE: 0=f32 out, 1=bf16 out, 2=both.
template <int TN, int ACT, int OMODE, bool RES>
__device__ void gemm_tile(char* smem,
    const unsigned short* __restrict__ A, int lda,
    const unsigned short* __restrict__ BT, int ldb, int Kloop,
    const float* __restrict__ bias, const float* __restrict__ res,
    float* __restrict__ outF, unsigned short* __restrict__ outB,
    int ldC, int Nstore, int m0, int n0, int koff) {
  constexpr int MR = (TN == 64) ? 2 : 4;
  constexpr int BUFS = 16384 + TN * 128;   // A 16KB + B per buffer
  const int tid = threadIdx.x;
  const int lane = tid & 63;
  const int wid = tid >> 6;
  const int rowbase = (TN == 64) ? wid * 32 : (wid >> 1) * 64;
  const int colbase = (TN == 64) ? 0 : (wid & 1) * 64;
  const unsigned short* Ag = A + (size_t)m0 * lda + koff;
  const unsigned short* Bg = BT + (size_t)n0 * ldb + koff;
  f32x4 acc[MR][4];
#pragma unroll
  for (int m = 0; m < MR; m++)
#pragma unroll
    for (int n = 0; n < 4; n++) acc[m][n] = 0.f;
  const int nt = Kloop >> 6;
  stage_tile<4>(Ag, lda, 0, smem, tid);
  stage_tile<TN / 32>(Bg, ldb, 0, smem + 16384, tid);
  __syncthreads();
  int cur = 0;
  const int rA = lane & 15, kq = lane >> 4;
  for (int t = 0; t < nt; ++t) {
    if (t + 1 < nt) {
      stage_tile<4>(Ag, lda, (t + 1) << 6, smem + (cur ^ 1) * BUFS, tid);
      stage_tile<TN / 32>(Bg, ldb, (t + 1) << 6, smem + (cur ^ 1) * BUFS + 16384, tid);
    }
    const char* la = smem + cur * BUFS;
    const char* lb = la + 16384;
#pragma unroll
    for (int kk = 0; kk < 2; ++kk) {
      int k8 = kk * 4 + kq;
      bf16x8 af[MR], bfr[4];
#pragma unroll
      for (int m = 0; m < MR; m++) af[m] = ld_frag(la, rowbase + m * 16 + rA, k8);
#pragma unroll
      for (int n = 0; n < 4; n++) bfr[n] = ld_frag(lb, colbase + n * 16 + rA, k8);
#pragma unroll
      for (int m = 0; m < MR; m++)
#pragma unroll
        for (int n = 0; n < 4; n++)
          acc[m][n] = __builtin_amdgcn_mfma_f32_16x16x32_bf16(af[m], bfr[n], acc[m][n], 0, 0, 0);
    }
    __syncthreads();
    cur ^= 1;
  }
  const int rb = m0 + rowbase + (kq << 2);
  const int cb = n0 + colbase + rA;
#pragma unroll
  for (int m = 0; m < MR; m++)
#pragma unroll
    for (int n = 0; n < 4; n++) {
      int cg = cb + n * 16;
      if (cg >= Nstore) continue;
      float bv = bias ? bias[cg] : 0.0f;
#pragma unroll
      for (int j = 0; j < 4; j++) {
        int rg = rb + m * 16 + j;
        float v = acc[m][n][j] + bv;
        if (RES) v += res[(size_t)rg * ldC + cg];
        if (ACT == 1) v = 0.5f * v * (1.0f + erff(v * 0.70710678118654752f));
        if (OMODE == 0) {
          outF[(size_t)rg * ldC + cg] = v;
        } else if (OMODE == 1) {
          outB[(size_t)rg * ldC + cg] = f2bf(v);
        } else {
          outF[(size_t)rg * ldC + cg] = v;
          outB[(size_t)rg * ldC + cg] = f2bf(v);
        }
      }
    }
}

// ---------- front1: wcast(img) + crop + zinit, all independent ----------
__global__ __launch_bounds__(256) void front1(
    const float* __restrict__ x, const float* __restrict__ tr, const float* __restrict__ hist,
    const float* __restrict__ w_img, const float* __restrict__ w_qkv, const float* __restrict__ w_o,
    const float* __restrict__ w_ff1, const float* __restrict__ w_ff2, const float* __restrict__ w_cls,
    unsigned short* BT_img, unsigned short* BT_qkv, unsigned short* BT_o,
    unsigned short* BT_ff1, unsigned short* BT_ff2, unsigned short* BT_cls,
    unsigned short* feats, float* z) {
  __shared__ __align__(16) char smem[16640];
  int bid = blockIdx.x;
  int tid = threadIdx.x;
  if (bid < 1024) {
    wcast_tile(smem, bid, w_img, w_qkv, w_o, w_ff1, w_ff2, w_cls,
               BT_img, BT_qkv, BT_o, BT_ff1, BT_ff2, BT_cls);
  } else if (bid < 1280) {
    int b = bid - 1024;
    int* xi = (int*)smem;
    int* yi = xi + 64;
    float px = tr[b * 4 + 0], py = tr[b * 4 + 1], zx = tr[b * 4 + 2], zy = tr[b * 4 + 3];
    float x1 = __fmul_rn(px, 448.0f);
    float y1 = __fmul_rn(py, 448.0f);
    float xs = fminf(__fsub_rn(512.0f, x1), __fadd_rn(__fmul_rn(zx, 448.0f), 64.0f));
    float ys = fminf(__fsub_rn(512.0f, y1), __fadd_rn(__fmul_rn(zy, 448.0f), 64.0f));
    if (tid < 64) {
      float u = __fmul_rn(__fmul_rn((float)tid, 0.015625f), xs);
      int v = (int)(__fadd_rn(floorf(u), x1));
      xi[tid] = min(max(v, 0), 511);
    } else if (tid < 128) {
      int tt = tid - 64;
      float u = __fmul_rn(__fmul_rn((float)tt, 0.015625f), ys);
      int v = (int)(__fadd_rn(floorf(u), y1));
      yi[tt] = min(max(v, 0), 511);
    }
    __syncthreads();
    const float* img = x + (size_t)b * 262144;
    for (int p = tid; p < 4096; p += 256) {
      int i = p >> 6, j = p & 63;
      float val = img[xi[i] * 512 + yi[j]] * 128.0f;
      feats[(size_t)b * 4096 + p] = f2bf(val);
    }
  } else {
    int idx = (bid - 1280) * 256 + tid;     // 1792 blocks * 256 = 458752 exactly
    int off = idx * 4;
    int b = off / 7168;
    int r = off - b * 7168;
    int i = r >> 10, c = r & 1023;
    float4 v = *(const float4*)(hist + (size_t)(i + 1) * 262144 + (size_t)b * 1024 + c);
    *(float4*)(z + (size_t)b * 8192 + i * 1024 + c) = v;
  }
}

// ---------- k_img: imgGEMM split-K x8 (256 blocks) + wcast rest (6144 blocks) ----------
__global__ __launch_bounds__(256) void k_img(
    const unsigned short* __restrict__ feats, const unsigned short* __restrict__ BT_img,
    float* __restrict__ part,
    const float* __restrict__ w_img, const float* __restrict__ w_qkv, const float* __restrict__ w_o,
    const float* __restrict__ w_ff1, const float* __restrict__ w_ff2, const float* __restrict__ w_cls,
    unsigned short* BT_img_d, unsigned short* BT_qkv, unsigned short* BT_o,
    unsigned short* BT_ff1, unsigned short* BT_ff2, unsigned short* BT_cls) {
  __shared__ __align__(16) char smem[49152];
  int bid = blockIdx.x;
  if (bid < 256) {
    int sk = bid >> 5, r = bid & 31, my = r >> 4, nx = r & 15;
    gemm_tile<64, 0, 0, false>(smem, feats, 4096, BT_img, 4096, 512,
                               nullptr, nullptr, part + (size_t)sk * 262144, nullptr,
                               1024, 1024, my * 128, nx * 64, sk * 512);
  } else {
    wcast_tile(smem, 1024 + bid - 256, w_img, w_qkv, w_o, w_ff1, w_ff2, w_cls,
               BT_img_d, BT_qkv, BT_o, BT_ff1, BT_ff2, BT_cls);
  }
}

// ---------- img reduce -> z[:,7,:] ----------
__global__ __launch_bounds__(256) void imgred(const float* __restrict__ part,
                                              const float* __restrict__ b_img,
                                              float* __restrict__ z) {
  int m = blockIdx.x, c = threadIdx.x * 4;
  float4 a = {0.f, 0.f, 0.f, 0.f};
  for (int p = 0; p < 8; ++p) {
    float4 v = *(const float4*)(part + (size_t)p * 262144 + m * 1024 + c);
    a.x += v.x; a.y += v.y; a.z += v.z; a.w += v.w;
  }
  float4 bv = *(const float4*)(b_img + c);
  a.x += bv.x; a.y += bv.y; a.z += bv.z; a.w += bv.w;
  *(float4*)(z + (size_t)m * 8192 + 7168 + c) = a;
}

// ---------- LayerNorm: z f32 [2048][1024] -> h bf16 (wave per row) ----------
__global__ __launch_bounds__(256) void ln_kernel(const float* __restrict__ z,
                                                 const float* __restrict__ sc,
                                                 const float* __restrict__ bi,
                                                 unsigned short* __restrict__ h) {
  int row = blockIdx.x * 4 + (threadIdx.x >> 6);
  int lane = threadIdx.x & 63;
  const float* zr = z + (size_t)row * 1024;
  float4 v[4];
  float s = 0.f, q = 0.f;
#pragma unroll
  for (int i = 0; i < 4; i++) {
    v[i] = *(const float4*)(zr + lane * 4 + i * 256);
    s += v[i].x + v[i].y + v[i].z + v[i].w;
    q += v[i].x * v[i].x + v[i].y * v[i].y + v[i].z * v[i].z + v[i].w * v[i].w;
  }
#pragma unroll
  for (int off = 32; off; off >>= 1) { s += __shfl_xor(s, off); q += __shfl_xor(q, off); }
  float mean = s * (1.0f / 1024.0f);
  float var = q * (1.0f / 1024.0f) - mean * mean;
  float rstd = rsqrtf(var + 1e-5f);
  u16x4* out = (u16x4*)(h + (size_t)row * 1024);
#pragma unroll
  for (int i = 0; i < 4; i++) {
    int c = lane * 4 + i * 256;
    float4 sv = *(const float4*)(sc + c);
    float4 bv = *(const float4*)(bi + c);
    u16x4 o;
    o.x = f2bf((v[i].x - mean) * rstd * sv.x + bv.x);
    o.y = f2bf((v[i].y - mean) * rstd * sv.y + bv.y);
    o.z = f2bf((v[i].z - mean) * rstd * sv.z + bv.z);
    o.w = f2bf((v[i].w - mean) * rstd * sv.w + bv.w);
    out[lane + i * 64] = o;
  }
}

// ---------- tiny attention: per (b,head), S=8, D=64, bf16 in/out ----------
__global__ __launch_bounds__(64) void attn_kernel(const unsigned short* __restrict__ qkv,
                                                  unsigned short* __restrict__ obuf) {
  int bh = blockIdx.x;
  int b = bh >> 3, hh = bh & 7;
  const unsigned short* base = qkv + (size_t)b * 8 * 1536;
  __shared__ float Q[8][64], K[8][64], V[8][64], S[8][8], P[8][8];
  int t = threadIdx.x;
#pragma unroll
  for (int i = 0; i < 8; i++) {
    Q[i][t] = bf2f(base[i * 1536 + hh * 64 + t]);
    K[i][t] = bf2f(base[i * 1536 + 512 + hh * 64 + t]);
    V[i][t] = bf2f(base[i * 1536 + 1024 + hh * 64 + t]);
  }
  __syncthreads();
  {
    int i = t >> 3, j = t & 7;
    float s = 0.f;
#pragma unroll
    for (int d = 0; d < 64; d++) s += Q[i][d] * K[j][d];
    S[i][j] = s * 0.125f;
  }
  __syncthreads();
  {
    int i = t >> 3, j = t & 7;
    float m = S[i][0];
#pragma unroll
    for (int jj = 1; jj < 8; jj++) m = fmaxf(m, S[i][jj]);
    float sum = 0.f;
#pragma unroll
    for (int jj = 0; jj < 8; jj++) sum += expf(S[i][jj] - m);
    P[i][j] = expf(S[i][j] - m) / sum;
  }
  __syncthreads();
#pragma unroll
  for (int i = 0; i < 8; i++) {
    float o = 0.f;
#pragma unroll
    for (int j = 0; j < 8; j++) o += P[i][j] * V[j][t];
    obuf[(size_t)(b * 8 + i) * 512 + hh * 64 + t] = f2bf(o);
  }
}

// ---------- standalone GEMM wrapper ----------
template <int TN, int ACT, int OMODE, bool RES>
__global__ __launch_bounds__(256) void gemm_k(
    const unsigned short* __restrict__ A, int lda,
    const unsigned short* __restrict__ BT, int ldb, int Kloop,
    const float* __restrict__ bias, const float* __restrict__ res,
    float* __restrict__ outF, unsigned short* __restrict__ outB,
    int ldC, int Nstore) {
  constexpr int BUFS = 16384 + TN * 128;
  __shared__ __align__(16) char smem[2 * BUFS];
  gemm_tile<TN, ACT, OMODE, RES>(smem, A, lda, BT, ldb, Kloop, bias, res, outF, outB,
                                 ldC, Nstore, blockIdx.y * 128, blockIdx.x * TN, 0);
}

// ---------- k_cls: cls GEMM split-K x8 (256 blocks) + transform head (256 blocks) ----------
__global__ __launch_bounds__(256) void k_cls(
    const unsigned short* __restrict__ tl, const unsigned short* __restrict__ BT_cls,
    float* __restrict__ part,
    const float* __restrict__ z, const float* __restrict__ w_tr,
    const float* __restrict__ b_tr, float* __restrict__ outF) {
  __shared__ __align__(16) char smem[49152];
  int bid = blockIdx.x;
  int tid = threadIdx.x;
  if (bid < 256) {
    int sk = bid >> 5, r = bid & 31, my = r >> 4, nx = r & 15;
    gemm_tile<64, 0, 0, false>(smem, tl, 8192, BT_cls, 8192, 1024,
                               nullptr, nullptr, part + (size_t)sk * 262144, nullptr,
                               1024, 1024, my * 128, nx * 64, sk * 1024);
  } else {
    int m = bid - 256;
    const float* row = z + (size_t)m * 8192;
    float a0 = 0.f, a1 = 0.f, a2 = 0.f, a3 = 0.f;
    for (int k = tid; k < 8192; k += 256) {
      float xv = row[k];
      const float* wr = w_tr + (size_t)k * 4;
      a0 += xv * wr[0]; a1 += xv * wr[1]; a2 += xv * wr[2]; a3 += xv * wr[3];
    }
    float (*red)[4] = (float (*)[4])smem;
    red[tid][0] = a0; red[tid][1] = a1; red[tid][2] = a2; red[tid][3] = a3;
    __syncthreads();
    for (int s = 128; s > 0; s >>= 1) {
      if (tid < s) {
#pragma unroll
        for (int o = 0; o < 4; o++) red[tid][o] += red[tid + s][o];
      }
      __syncthreads();
    }
    if (tid < 4) {
      float v = red[0][tid] + b_tr[tid];
      outF[256000 + m * 4 + tid] = 1.0f / (1.0f + expf(-v));
    }
  }
}

// ---------- cls reduce -> outF[:, :1000] ----------
__global__ __launch_bounds__(256) void clsred(const float* __restrict__ part,
                                              const float* __restrict__ b_cls,
                                              float* __restrict__ outF) {
  int m = blockIdx.x, c = threadIdx.x * 4;
  float4 a = {0.f, 0.f, 0.f, 0.f};
  for (int p = 0; p < 8; ++p) {
    float4 v = *(const float4*)(part + (size_t)p * 262144 + m * 1024 + c);
    a.x += v.x; a.y += v.y; a.z += v.z; a.w += v.w;
  }
  if (c >= 1000) return;
  float* drow = outF + (size_t)m * 1000;
  float vals[4] = {a.x, a.y, a.z, a.w};
  if (c + 3 < 1000) {
    *(float4*)(drow + c) = make_float4(vals[0] + b_cls[c], vals[1] + b_cls[c + 1],
                                       vals[2] + b_cls[c + 2], vals[3] + b_cls[c + 3]);
  } else {
    for (int j = 0; j < 4 && c + j < 1000; ++j) drow[c + j] = vals[j] + b_cls[c + j];
  }
}

// ---------- launch ----------
extern "C" void kernel_launch(void* const* d_in, const int* in_sizes, int n_in,
                              void* d_out, int out_size, void* d_ws, size_t ws_size,
                              hipStream_t stream) {
  const float* x      = (const float*)d_in[0];
  const float* tr     = (const float*)d_in[1];
  const float* hist   = (const float*)d_in[2];
  const float* w_img  = (const float*)d_in[3];
  const float* b_img  = (const float*)d_in[4];
  const float* ln1_s  = (const float*)d_in[5];
  const float* ln1_b  = (const float*)d_in[6];
  const float* w_qkv  = (const float*)d_in[7];
  const float* w_o    = (const float*)d_in[8];
  const float* b_o    = (const float*)d_in[9];
  const float* ln2_s  = (const float*)d_in[10];
  const float* ln2_b  = (const float*)d_in[11];
  const float* w_ff1  = (const float*)d_in[12];
  const float* b_ff1  = (const float*)d_in[13];
  const float* w_ff2  = (const float*)d_in[14];
  const float* b_ff2  = (const float*)d_in[15];
  const float* w_cls  = (const float*)d_in[16];
  const float* b_cls  = (const float*)d_in[17];
  const float* w_tr   = (const float*)d_in[18];
  const float* b_tr   = (const float*)d_in[19];
  float* outF = (float*)d_out;

  char* w = (char*)d_ws;
  auto alloc = [&](size_t bytes) { char* p = w; w += (bytes + 255) & ~(size_t)255; return p; };
  unsigned short* BT_img = (unsigned short*)alloc((size_t)1024 * 4096 * 2);
  unsigned short* BT_qkv = (unsigned short*)alloc((size_t)4 * 1536 * 1024 * 2);
  unsigned short* BT_o   = (unsigned short*)alloc((size_t)4 * 1024 * 512 * 2);
  unsigned short* BT_ff1 = (unsigned short*)alloc((size_t)4 * 1024 * 1024 * 2);
  unsigned short* BT_ff2 = (unsigned short*)alloc((size_t)4 * 1024 * 1024 * 2);
  unsigned short* BT_cls = (unsigned short*)alloc((size_t)1024 * 8192 * 2);
  unsigned short* feats  = (unsigned short*)alloc((size_t)256 * 4096 * 2);
  float*          z      = (float*)alloc((size_t)2048 * 1024 * 4);
  unsigned short* h      = (unsigned short*)alloc((size_t)2048 * 1024 * 2);  // also tl
  unsigned short* qkvb   = (unsigned short*)alloc((size_t)2048 * 1536 * 2);
  unsigned short* obuf   = (unsigned short*)alloc((size_t)2048 * 512 * 2);
  unsigned short* g      = (unsigned short*)alloc((size_t)2048 * 1024 * 2);
  float*          part   = (float*)alloc((size_t)8 * 256 * 1024 * 4);
  if ((size_t)(w - (char*)d_ws) > ws_size) return;

  // front: wcast(img) + crop + zinit in one launch (independent work)
  front1<<<3072, 256, 0, stream>>>(x, tr, hist, w_img, w_qkv, w_o, w_ff1, w_ff2, w_cls,
                                   BT_img, BT_qkv, BT_o, BT_ff1, BT_ff2, BT_cls, feats, z);
  // img GEMM overlapped with remaining weight casting
  k_img<<<6400, 256, 0, stream>>>(feats, BT_img, part,
                                  w_img, w_qkv, w_o, w_ff1, w_ff2, w_cls,
                                  BT_img, BT_qkv, BT_o, BT_ff1, BT_ff2, BT_cls);
  imgred<<<256, 256, 0, stream>>>(part, b_img, z);

  for (int i = 0; i < 4; ++i) {
    const unsigned short* Wq = BT_qkv + (size_t)i * 1536 * 1024;
    const unsigned short* Wo = BT_o   + (size_t)i * 1024 * 512;
    const unsigned short* W1 = BT_ff1 + (size_t)i * 1024 * 1024;
    const unsigned short* W2 = BT_ff2 + (size_t)i * 1024 * 1024;
    ln_kernel<<<512, 256, 0, stream>>>(z, ln1_s + i * 1024, ln1_b + i * 1024, h);
    gemm_k<128, 0, 1, false><<<dim3(12, 16), 256, 0, stream>>>(
        h, 1024, Wq, 1024, 1024, nullptr, nullptr, nullptr, qkvb, 1536, 1536);
    attn_kernel<<<2048, 64, 0, stream>>>(qkvb, obuf);
    gemm_k<64, 0, 0, true><<<dim3(16, 16), 256, 0, stream>>>(
        obuf, 512, Wo, 512, 512, b_o + i * 1024, z, z, nullptr, 1024, 1024);
    ln_kernel<<<512, 256, 0, stream>>>(z, ln2_s + i * 1024, ln2_b + i * 1024, h);
    gemm_k<64, 1, 1, false><<<dim3(16, 16), 256, 0, stream>>>(
        h, 1024, W1, 1024, 1024, b_ff1 + i * 1024, nullptr, nullptr, g, 1024, 1024);
    if (i < 3) {
      gemm_k<64, 0, 0, true><<<dim3(16, 16), 256, 0, stream>>>(
          g, 1024, W2, 1024, 1024, b_ff2 + i * 1024, z, z, nullptr, 1024, 1024);
    } else {
      gemm_k<64, 0, 2, true><<<dim3(16, 16), 256, 0, stream>>>(
          g, 1024, W2, 1024, 1024, b_ff2 + i * 1024, z, z, h, 1024, 1024);
    }
  }

  // tail: cls GEMM + transform head in one launch, then reduce
  k_cls<<<512, 256, 0, stream>>>(h, BT_cls, part, z, w_tr, b_tr, outF);
  clsred<<<256, 256, 0, stream>>>(part, b_cls, outF);
}

// Round 6
// 373.286 us; speedup vs baseline: 3.7175x; 1.0098x over previous
//
#include <hip/hip_runtime.h>
#include <cstdint>
#include <cstddef>

// ---------- types ----------
typedef __attribute__((ext_vector_type(8))) __bf16 bf16x8;
typedef __attribute__((ext_vector_type(8))) unsigned short u16x8;
typedef __attribute__((ext_vector_type(4))) float f32x4;
typedef __attribute__((ext_vector_type(4))) unsigned short u16x4;

__device__ __forceinline__ unsigned short f2bf(float f) {
  unsigned int u = __builtin_bit_cast(unsigned int, f);
  u += 0x7fffu + ((u >> 16) & 1u);           // RNE
  return (unsigned short)(u >> 16);
}
__device__ __forceinline__ float bf2f(unsigned short u) {
  return __builtin_bit_cast(float, ((unsigned int)u) << 16);
}

// ---------- weight cast+transpose, one 64x64 tile (tile id in [0,7168)) ----------
__device__ void wcast_tile(char* smemc, int bid,
    const float* s_img, const float* s_qkv, const float* s_o,
    const float* s_ff1, const float* s_ff2, const float* s_cls,
    unsigned short* d_img, unsigned short* d_qkv, unsigned short* d_o,
    unsigned short* d_ff1, unsigned short* d_ff2, unsigned short* d_cls) {
  float (*tile)[65] = (float (*)[65])smemc;
  const float* src; unsigned short* dst; int K, N, Npad, rel;
  if (bid < 1024)       { src = s_img; dst = d_img; K = 4096; N = 1024; Npad = 1024; rel = bid; }
  else if (bid < 2560)  { rel = bid - 1024; int l = rel / 384; rel -= l * 384;
                          src = s_qkv + (size_t)l * 1024 * 1536; dst = d_qkv + (size_t)l * 1536 * 1024;
                          K = 1024; N = 1536; Npad = 1536; }
  else if (bid < 3072)  { rel = bid - 2560; int l = rel / 128; rel -= l * 128;
                          src = s_o   + (size_t)l * 512 * 1024;  dst = d_o   + (size_t)l * 1024 * 512;
                          K = 512;  N = 1024; Npad = 1024; }
  else if (bid < 4096)  { rel = bid - 3072; int l = rel / 256; rel -= l * 256;
                          src = s_ff1 + (size_t)l * 1024 * 1024; dst = d_ff1 + (size_t)l * 1024 * 1024;
                          K = 1024; N = 1024; Npad = 1024; }
  else if (bid < 5120)  { rel = bid - 4096; int l = rel / 256; rel -= l * 256;
                          src = s_ff2 + (size_t)l * 1024 * 1024; dst = d_ff2 + (size_t)l * 1024 * 1024;
                          K = 1024; N = 1024; Npad = 1024; }
  else                  { rel = bid - 5120; src = s_cls; dst = d_cls; K = 8192; N = 1000; Npad = 1024; }
  int tilesX = Npad >> 6;
  int nx = rel % tilesX, ky = rel / tilesX;
  int n0 = nx << 6, k0 = ky << 6;
  int t = threadIdx.x;
#pragma unroll
  for (int i = 0; i < 4; ++i) {
    int slot = t + i * 256;
    int kk = slot >> 4, cq = slot & 15;
    int n = n0 + cq * 4;
    float4 v;
    if (n + 3 < N) v = *(const float4*)(src + (size_t)(k0 + kk) * N + n);
    else {
      v.x = v.y = v.z = v.w = 0.0f;
      if (n < N)     v.x = src[(size_t)(k0 + kk) * N + n];
      if (n + 1 < N) v.y = src[(size_t)(k0 + kk) * N + n + 1];
      if (n + 2 < N) v.z = src[(size_t)(k0 + kk) * N + n + 2];
      if (n + 3 < N) v.w = src[(size_t)(k0 + kk) * N + n + 3];
    }
    tile[kk][cq * 4 + 0] = v.x;
    tile[kk][cq * 4 + 1] = v.y;
    tile[kk][cq * 4 + 2] = v.z;
    tile[kk][cq * 4 + 3] = v.w;
  }
  __syncthreads();
#pragma unroll
  for (int i = 0; i < 4; ++i) {
    int slot = t + i * 256;
    int n = slot >> 4, kq = slot & 15;
    u16x4 o;
    o.x = f2bf(tile[kq * 4 + 0][n]);
    o.y = f2bf(tile[kq * 4 + 1][n]);
    o.z = f2bf(tile[kq * 4 + 2][n]);
    o.w = f2bf(tile[kq * 4 + 3][n]);
    *(u16x4*)(dst + (size_t)(n0 + n) * K + k0 + kq * 4) = o;
  }
}

// ---------- GEMM pieces ----------
template <int ITERS>
__device__ __forceinline__ void stage_tile(const unsigned short* __restrict__ g, int ld,
                                           int k0, char* lbase, int tid) {
#pragma unroll
  for (int it = 0; it < ITERS; ++it) {
    int c = tid + it * 256;              // 16B chunk id; 8 chunks per 64-k row
    int r = c >> 3;
    int c8 = (c & 7) ^ (r & 7);          // pre-swizzled global source (m173 pattern)
    const unsigned short* src = g + (size_t)r * ld + (k0 + c8 * 8);
    char* dst = lbase + c * 16;          // linear LDS dest
    __builtin_amdgcn_global_load_lds((__attribute__((address_space(1))) void*)src,
                                     (__attribute__((address_space(3))) void*)dst, 16, 0, 0);
  }
}

__device__ __forceinline__ bf16x8 ld_frag(const char* base, int row, int k8) {
  int off = (row << 7) + ((k8 ^ (row & 7)) << 4);   // XOR swizzle (G4)
  return *(const bf16x8*)(base + off);
}

// TM=128. TN=64: wave owns 32x64 (MR=2). OMODE: 0=f32 out, 1=bf16 out, 2=both.
template <int TN, int ACT, int OMODE, bool RES>
__device__ void gemm_tile(char* smem,
    const unsigned short* __restrict__ A, int lda,
    const unsigned short* __restrict__ BT, int ldb, int Kloop,
    const float* __restrict__ bias, const float* __restrict__ res,
    float* __restrict__ outF, unsigned short* __restrict__ outB,
    int ldC, int Nstore, int m0, int n0, int koff) {
  constexpr int MR = (TN == 64) ? 2 : 4;
  constexpr int BUFS = 16384 + TN * 128;
  const int tid = threadIdx.x;
  const int lane = tid & 63;
  const int wid = tid >> 6;
  const int rowbase = (TN == 64) ? wid * 32 : (wid >> 1) * 64;
  const int colbase = (TN == 64) ? 0 : (wid & 1) * 64;
  const unsigned short* Ag = A + (size_t)m0 * lda + koff;
  const unsigned short* Bg = BT + (size_t)n0 * ldb + koff;
  f32x4 acc[MR][4];
#pragma unroll
  for (int m = 0; m < MR; m++)
#pragma unroll
    for (int n = 0; n < 4; n++) acc[m][n] = 0.f;
  const int nt = Kloop >> 6;
  stage_tile<4>(Ag, lda, 0, smem, tid);
  stage_tile<TN / 32>(Bg, ldb, 0, smem + 16384, tid);
  __syncthreads();
  int cur = 0;
  const int rA = lane & 15, kq = lane >> 4;
  for (int t = 0; t < nt; ++t) {
    if (t + 1 < nt) {
      stage_tile<4>(Ag, lda, (t + 1) << 6, smem + (cur ^ 1) * BUFS, tid);
      stage_tile<TN / 32>(Bg, ldb, (t + 1) << 6, smem + (cur ^ 1) * BUFS + 16384, tid);
    }
    const char* la = smem + cur * BUFS;
    const char* lb = la + 16384;
#pragma unroll
    for (int kk = 0; kk < 2; ++kk) {
      int k8 = kk * 4 + kq;
      bf16x8 af[MR], bfr[4];
#pragma unroll
      for (int m = 0; m < MR; m++) af[m] = ld_frag(la, rowbase + m * 16 + rA, k8);
#pragma unroll
      for (int n = 0; n < 4; n++) bfr[n] = ld_frag(lb, colbase + n * 16 + rA, k8);
#pragma unroll
      for (int m = 0; m < MR; m++)
#pragma unroll
        for (int n = 0; n < 4; n++)
          acc[m][n] = __builtin_amdgcn_mfma_f32_16x16x32_bf16(af[m], bfr[n], acc[m][n], 0, 0, 0);
    }
    __syncthreads();
    cur ^= 1;
  }
  const int rb = m0 + rowbase + (kq << 2);
  const int cb = n0 + colbase + rA;
#pragma unroll
  for (int m = 0; m < MR; m++)
#pragma unroll
    for (int n = 0; n < 4; n++) {
      int cg = cb + n * 16;
      if (cg >= Nstore) continue;
      float bv = bias ? bias[cg] : 0.0f;
#pragma unroll
      for (int j = 0; j < 4; j++) {
        int rg = rb + m * 16 + j;
        float v = acc[m][n][j] + bv;
        if (RES) v += res[(size_t)rg * ldC + cg];
        if (ACT == 1) v = 0.5f * v * (1.0f + erff(v * 0.70710678118654752f));
        if (OMODE == 0) {
          outF[(size_t)rg * ldC + cg] = v;
        } else if (OMODE == 1) {
          outB[(size_t)rg * ldC + cg] = f2bf(v);
        } else {
          outF[(size_t)rg * ldC + cg] = v;
          outB[(size_t)rg * ldC + cg] = f2bf(v);
        }
      }
    }
}

// ---------- fused qkv GEMM + attention ----------
// grid (8 heads, 16 row-groups). Block: 128 rows (16 batches) x 192 cols (q|k|v of one head).
// Waves 2x2: wave owns 64 rows x 96 cols (MR=4, NR=6). Then attention epilogue.
__global__ __launch_bounds__(256) void qkvattn(
    const unsigned short* __restrict__ h,      // [2048][1024] bf16
    const unsigned short* __restrict__ BTq,    // [1536][1024] bf16 (layer slice)
    unsigned short* __restrict__ obuf) {       // [2048][512] bf16
  __shared__ __align__(16) char smem[81920];   // 2 x (A 16KB + B 24KB); epilogue slab reuses
  const int tid = threadIdx.x, lane = tid & 63, wid = tid >> 6;
  const int hh = blockIdx.x, my = blockIdx.y;
  const int m0 = my << 7;
  const int wr = wid >> 1, wc = wid & 1;
  const unsigned short* Ag = h + (size_t)m0 * 1024;
  const unsigned short* Bseg0 = BTq + (size_t)(hh * 64) * 1024;
  const unsigned short* Bseg1 = BTq + (size_t)(512 + hh * 64) * 1024;
  const unsigned short* Bseg2 = BTq + (size_t)(1024 + hh * 64) * 1024;
  constexpr int BUFS = 40960;
  f32x4 acc[4][6];
#pragma unroll
  for (int m = 0; m < 4; m++)
#pragma unroll
    for (int n = 0; n < 6; n++) acc[m][n] = 0.f;
  const int rA = lane & 15, kq = lane >> 4;
  stage_tile<4>(Ag, 1024, 0, smem, tid);
  stage_tile<2>(Bseg0, 1024, 0, smem + 16384, tid);
  stage_tile<2>(Bseg1, 1024, 0, smem + 24576, tid);
  stage_tile<2>(Bseg2, 1024, 0, smem + 32768, tid);
  __syncthreads();
  int cur = 0;
  for (int t = 0; t < 16; ++t) {
    if (t + 1 < 16) {
      char* nb = smem + (cur ^ 1) * BUFS;
      stage_tile<4>(Ag, 1024, (t + 1) << 6, nb, tid);
      stage_tile<2>(Bseg0, 1024, (t + 1) << 6, nb + 16384, tid);
      stage_tile<2>(Bseg1, 1024, (t + 1) << 6, nb + 24576, tid);
      stage_tile<2>(Bseg2, 1024, (t + 1) << 6, nb + 32768, tid);
    }
    const char* la = smem + cur * BUFS;
    const char* lb = la + 16384;
#pragma unroll
    for (int kk = 0; kk < 2; ++kk) {
      int k8 = kk * 4 + kq;
      bf16x8 af[4], bfr[6];
#pragma unroll
      for (int m = 0; m < 4; m++) af[m] = ld_frag(la, wr * 64 + m * 16 + rA, k8);
#pragma unroll
      for (int n = 0; n < 6; n++) {
        int cidx = wc * 96 + n * 16 + rA;                  // 0..191
        bfr[n] = ld_frag(lb + (cidx >> 6) * 8192, cidx & 63, k8);
      }
#pragma unroll
      for (int m = 0; m < 4; m++)
#pragma unroll
        for (int n = 0; n < 6; n++)
          acc[m][n] = __builtin_amdgcn_mfma_f32_16x16x32_bf16(af[m], bfr[n], acc[m][n], 0, 0, 0);
    }
    __syncthreads();
    cur ^= 1;
  }
  // ---- write q|k|v slab [128][192] bf16 at smem base ----
  unsigned short* slab = (unsigned short*)smem;
  float* Sb = (float*)(smem + 49152 + wid * 1024);   // per-wave [4 batch][8][8] f32
#pragma unroll
  for (int m = 0; m < 4; m++)
#pragma unroll
    for (int n = 0; n < 6; n++) {
      int r = wr * 64 + m * 16 + (kq << 2);
      int c = wc * 96 + n * 16 + rA;
#pragma unroll
      for (int j = 0; j < 4; j++) slab[(size_t)(r + j) * 192 + c] = f2bf(acc[m][n][j]);
    }
  __syncthreads();
  // ---- attention: wave handles 4 batches = slab rows [wid*32, wid*32+32) ----
  {
    int l15 = lane & 15;
    int rbase = wid * 32 + (lane >> 4) * 8;      // q/k/v rows of this lane's batch
    int j = l15 & 7;                              // fixed k-row per lane
    const u16x8* krow = (const u16x8*)(slab + (size_t)(rbase + j) * 192 + 64);
    u16x8 kv8[8];
#pragma unroll
    for (int q8 = 0; q8 < 8; ++q8) kv8[q8] = krow[q8];
#pragma unroll
    for (int e4 = 0; e4 < 4; ++e4) {
      int e = l15 + 16 * e4;
      int i = e >> 3;
      const u16x8* qrow = (const u16x8*)(slab + (size_t)(rbase + i) * 192);
      float s = 0.f;
#pragma unroll
      for (int q8 = 0; q8 < 8; ++q8) {
        u16x8 qv = qrow[q8];
#pragma unroll
        for (int u = 0; u < 8; ++u) s = fmaf(bf2f(qv[u]), bf2f(kv8[q8][u]), s);
      }
      Sb[((lane >> 4) * 8 + i) * 8 + (e & 7)] = s * 0.125f;
    }
    // softmax: lanes 0..31, one row each (batch = lane>>3, i = lane&7)
    if (lane < 32) {
      float4 r0 = ((const float4*)(Sb + lane * 8))[0];
      float4 r1 = ((const float4*)(Sb + lane * 8))[1];
      float mx = fmaxf(fmaxf(fmaxf(r0.x, r0.y), fmaxf(r0.z, r0.w)),
                       fmaxf(fmaxf(r1.x, r1.y), fmaxf(r1.z, r1.w)));
      float e0 = expf(r0.x - mx), e1 = expf(r0.y - mx), e2 = expf(r0.z - mx), e3 = expf(r0.w - mx);
      float e4_ = expf(r1.x - mx), e5 = expf(r1.y - mx), e6 = expf(r1.z - mx), e7 = expf(r1.w - mx);
      float inv = 1.0f / (e0 + e1 + e2 + e3 + e4_ + e5 + e6 + e7);
      ((float4*)(Sb + lane * 8))[0] = make_float4(e0 * inv, e1 * inv, e2 * inv, e3 * inv);
      ((float4*)(Sb + lane * 8))[1] = make_float4(e4_ * inv, e5 * inv, e6 * inv, e7 * inv);
    }
    // PV: lane = d (0..63)
#pragma unroll
    for (int b4 = 0; b4 < 4; ++b4) {
      int rb2 = wid * 32 + b4 * 8;
      float vreg[8];
#pragma unroll
      for (int jj = 0; jj < 8; ++jj) vreg[jj] = bf2f(slab[(size_t)(rb2 + jj) * 192 + 128 + lane]);
      int browg = (my * 16 + wid * 4 + b4) * 8;
#pragma unroll
      for (int i = 0; i < 8; ++i) {
        float4 p0 = ((const float4*)(Sb + (b4 * 8 + i) * 8))[0];
        float4 p1 = ((const float4*)(Sb + (b4 * 8 + i) * 8))[1];
        float o = p0.x * vreg[0] + p0.y * vreg[1] + p0.z * vreg[2] + p0.w * vreg[3] +
                  p1.x * vreg[4] + p1.y * vreg[5] + p1.z * vreg[6] + p1.w * vreg[7];
        obuf[(size_t)(browg + i) * 512 + hh * 64 + lane] = f2bf(o);
      }
    }
  }
}

// ---------- front1: wcast(img) + crop + zinit ----------
__global__ __launch_bounds__(256) void front1(
    const float* __restrict__ x, const float* __restrict__ tr, const float* __restrict__ hist,
    const float* __restrict__ w_img, const float* __restrict__ w_qkv, const float* __restrict__ w_o,
    const float* __restrict__ w_ff1, const float* __restrict__ w_ff2, const float* __restrict__ w_cls,
    unsigned short* BT_img, unsigned short* BT_qkv, unsigned short* BT_o,
    unsigned short* BT_ff1, unsigned short* BT_ff2, unsigned short* BT_cls,
    unsigned short* feats, float* z) {
  __shared__ __align__(16) char smem[16640];
  int bid = blockIdx.x;
  int tid = threadIdx.x;
  if (bid < 1024) {
    wcast_tile(smem, bid, w_img, w_qkv, w_o, w_ff1, w_ff2, w_cls,
               BT_img, BT_qkv, BT_o, BT_ff1, BT_ff2, BT_cls);
  } else if (bid < 1280) {
    int b = bid - 1024;
    int* xi = (int*)smem;
    int* yi = xi + 64;
    float px = tr[b * 4 + 0], py = tr[b * 4 + 1], zx = tr[b * 4 + 2], zy = tr[b * 4 + 3];
    float x1 = __fmul_rn(px, 448.0f);
    float y1 = __fmul_rn(py, 448.0f);
    float xs = fminf(__fsub_rn(512.0f, x1), __fadd_rn(__fmul_rn(zx, 448.0f), 64.0f));
    float ys = fminf(__fsub_rn(512.0f, y1), __fadd_rn(__fmul_rn(zy, 448.0f), 64.0f));
    if (tid < 64) {
      float u = __fmul_rn(__fmul_rn((float)tid, 0.015625f), xs);
      int v = (int)(__fadd_rn(floorf(u), x1));
      xi[tid] = min(max(v, 0), 511);
    } else if (tid < 128) {
      int tt = tid - 64;
      float u = __fmul_rn(__fmul_rn((float)tt, 0.015625f), ys);
      int v = (int)(__fadd_rn(floorf(u), y1));
      yi[tt] = min(max(v, 0), 511);
    }
    __syncthreads();
    const float* img = x + (size_t)b * 262144;
    for (int p = tid; p < 4096; p += 256) {
      int i = p >> 6, j = p & 63;
      float val = img[xi[i] * 512 + yi[j]] * 128.0f;
      feats[(size_t)b * 4096 + p] = f2bf(val);
    }
  } else {
    int idx = (bid - 1280) * 256 + tid;     // 1792 blocks * 256 = 458752 exactly
    int off = idx * 4;
    int b = off / 7168;
    int r = off - b * 7168;
    int i = r >> 10, c = r & 1023;
    float4 v = *(const float4*)(hist + (size_t)(i + 1) * 262144 + (size_t)b * 1024 + c);
    *(float4*)(z + (size_t)b * 8192 + i * 1024 + c) = v;
  }
}

// ---------- k_img: imgGEMM split-K x8 (256 blocks) + wcast rest (6144 blocks) ----------
__global__ __launch_bounds__(256) void k_img(
    const unsigned short* __restrict__ feats, const unsigned short* __restrict__ BT_img,
    float* __restrict__ part,
    const float* __restrict__ w_img, const float* __restrict__ w_qkv, const float* __restrict__ w_o,
    const float* __restrict__ w_ff1, const float* __restrict__ w_ff2, const float* __restrict__ w_cls,
    unsigned short* BT_img_d, unsigned short* BT_qkv, unsigned short* BT_o,
    unsigned short* BT_ff1, unsigned short* BT_ff2, unsigned short* BT_cls) {
  __shared__ __align__(16) char smem[49152];
  int bid = blockIdx.x;
  if (bid < 256) {
    int sk = bid >> 5, r = bid & 31, my = r >> 4, nx = r & 15;
    gemm_tile<64, 0, 0, false>(smem, feats, 4096, BT_img, 4096, 512,
                               nullptr, nullptr, part + (size_t)sk * 262144, nullptr,
                               1024, 1024, my * 128, nx * 64, sk * 512);
  } else {
    wcast_tile(smem, 1024 + bid - 256, w_img, w_qkv, w_o, w_ff1, w_ff2, w_cls,
               BT_img_d, BT_qkv, BT_o, BT_ff1, BT_ff2, BT_cls);
  }
}

// ---------- LayerNorm one row (wave-level helper) ----------
__device__ __forceinline__ void ln_row(const float* __restrict__ z, int row,
                                       const float* __restrict__ sc, const float* __restrict__ bi,
                                       unsigned short* __restrict__ h) {
  int lane = threadIdx.x & 63;
  const float* zr = z + (size_t)row * 1024;
  float4 v[4];
  float s = 0.f, q = 0.f;
#pragma unroll
  for (int i = 0; i < 4; i++) {
    v[i] = *(const float4*)(zr + lane * 4 + i * 256);
    s += v[i].x + v[i].y + v[i].z + v[i].w;
    q += v[i].x * v[i].x + v[i].y * v[i].y + v[i].z * v[i].z + v[i].w * v[i].w;
  }
#pragma unroll
  for (int off = 32; off; off >>= 1) { s += __shfl_xor(s, off); q += __shfl_xor(q, off); }
  float mean = s * (1.0f / 1024.0f);
  float var = q * (1.0f / 1024.0f) - mean * mean;
  float rstd = rsqrtf(var + 1e-5f);
  u16x4* out = (u16x4*)(h + (size_t)row * 1024);
#pragma unroll
  for (int i = 0; i < 4; i++) {
    int c = lane * 4 + i * 256;
    float4 sv = *(const float4*)(sc + c);
    float4 bv = *(const float4*)(bi + c);
    u16x4 o;
    o.x = f2bf((v[i].x - mean) * rstd * sv.x + bv.x);
    o.y = f2bf((v[i].y - mean) * rstd * sv.y + bv.y);
    o.z = f2bf((v[i].z - mean) * rstd * sv.z + bv.z);
    o.w = f2bf((v[i].w - mean) * rstd * sv.w + bv.w);
    out[lane + i * 64] = o;
  }
}

// ---------- imgred + ln1(layer 0): block m handles batch m ----------
__global__ __launch_bounds__(256) void imgred_ln(
    const float* __restrict__ part, const float* __restrict__ b_img, float* __restrict__ z,
    const float* __restrict__ sc, const float* __restrict__ bi,
    unsigned short* __restrict__ h) {
  __shared__ float ws[8];
  int m = blockIdx.x, tid = threadIdx.x;
  int lane = tid & 63, wid = tid >> 6;
  int c = tid * 4;
  float4 a = {0.f, 0.f, 0.f, 0.f};
  for (int p = 0; p < 8; ++p) {
    float4 v = *(const float4*)(part + (size_t)p * 262144 + m * 1024 + c);
    a.x += v.x; a.y += v.y; a.z += v.z; a.w += v.w;
  }
  float4 bv = *(const float4*)(b_img + c);
  a.x += bv.x; a.y += bv.y; a.z += bv.z; a.w += bv.w;
  *(float4*)(z + (size_t)m * 8192 + 7168 + c) = a;
  // LN row 7 from registers (block-wide stats)
  float s = a.x + a.y + a.z + a.w;
  float q = a.x * a.x + a.y * a.y + a.z * a.z + a.w * a.w;
#pragma unroll
  for (int off = 32; off; off >>= 1) { s += __shfl_xor(s, off); q += __shfl_xor(q, off); }
  if (lane == 0) { ws[wid * 2] = s; ws[wid * 2 + 1] = q; }
  __syncthreads();
  float S4 = ws[0] + ws[2] + ws[4] + ws[6];
  float Q4 = ws[1] + ws[3] + ws[5] + ws[7];
  float mean = S4 * (1.0f / 1024.0f);
  float var = Q4 * (1.0f / 1024.0f) - mean * mean;
  float rstd = rsqrtf(var + 1e-5f);
  float4 sv = *(const float4*)(sc + c);
  float4 bb = *(const float4*)(bi + c);
  u16x4 o;
  o.x = f2bf((a.x - mean) * rstd * sv.x + bb.x);
  o.y = f2bf((a.y - mean) * rstd * sv.y + bb.y);
  o.z = f2bf((a.z - mean) * rstd * sv.z + bb.z);
  o.w = f2bf((a.w - mean) * rstd * sv.w + bb.w);
  *(u16x4*)(h + (size_t)(m * 8 + 7) * 1024 + c) = o;
  // LN rows 0..6 (already in z from zinit)
#pragma unroll
  for (int rr = 0; rr < 2; ++rr) {
    int r = wid * 2 + rr;
    if (r < 7) ln_row(z, m * 8 + r, sc, bi, h);
  }
}

// ---------- LayerNorm kernel (wave per row) ----------
__global__ __launch_bounds__(256) void ln_kernel(const float* __restrict__ z,
                                                 const float* __restrict__ sc,
                                                 const float* __restrict__ bi,
                                                 unsigned short* __restrict__ h) {
  int row = blockIdx.x * 4 + (threadIdx.x >> 6);
  ln_row(z, row, sc, bi, h);
}

// ---------- standalone GEMM wrapper ----------
template <int TN, int ACT, int OMODE, bool RES>
__global__ __launch_bounds__(256) void gemm_k(
    const unsigned short* __restrict__ A, int lda,
    const unsigned short* __restrict__ BT, int ldb, int Kloop,
    const float* __restrict__ bias, const float* __restrict__ res,
    float* __restrict__ outF, unsigned short* __restrict__ outB,
    int ldC, int Nstore) {
  constexpr int BUFS = 16384 + TN * 128;
  __shared__ __align__(16) char smem[2 * BUFS];
  gemm_tile<TN, ACT, OMODE, RES>(smem, A, lda, BT, ldb, Kloop, bias, res, outF, outB,
                                 ldC, Nstore, blockIdx.y * 128, blockIdx.x * TN, 0);
}

// ---------- k_cls: cls GEMM split-K x8 (256 blocks) + transform head (256 blocks) ----------
__global__ __launch_bounds__(256) void k_cls(
    const unsigned short* __restrict__ tl, const unsigned short* __restrict__ BT_cls,
    float* __restrict__ part,
    const float* __restrict__ z, const float* __restrict__ w_tr,
    const float* __restrict__ b_tr, float* __restrict__ outF) {
  __shared__ __align__(16) char smem[49152];
  int bid = blockIdx.x;
  int tid = threadIdx.x;
  if (bid < 256) {
    int sk = bid >> 5, r = bid & 31, my = r >> 4, nx = r & 15;
    gemm_tile<64, 0, 0, false>(smem, tl, 8192, BT_cls, 8192, 1024,
                               nullptr, nullptr, part + (size_t)sk * 262144, nullptr,
                               1024, 1024, my * 128, nx * 64, sk * 1024);
  } else {
    int m = bid - 256;
    const float* row = z + (size_t)m * 8192;
    float a0 = 0.f, a1 = 0.f, a2 = 0.f, a3 = 0.f;
    for (int k = tid; k < 8192; k += 256) {
      float xv = row[k];
      const float* wr = w_tr + (size_t)k * 4;
      a0 += xv * wr[0]; a1 += xv * wr[1]; a2 += xv * wr[2]; a3 += xv * wr[3];
    }
    float (*red)[4] = (float (*)[4])smem;
    red[tid][0] = a0; red[tid][1] = a1; red[tid][2] = a2; red[tid][3] = a3;
    __syncthreads();
    for (int s = 128; s > 0; s >>= 1) {
      if (tid < s) {
#pragma unroll
        for (int o = 0; o < 4; o++) red[tid][o] += red[tid + s][o];
      }
      __syncthreads();
    }
    if (tid < 4) {
      float v = red[0][tid] + b_tr[tid];
      outF[256000 + m * 4 + tid] = 1.0f / (1.0f + expf(-v));
    }
  }
}

// ---------- cls reduce -> outF[:, :1000] ----------
__global__ __launch_bounds__(256) void clsred(const float* __restrict__ part,
                                              const float* __restrict__ b_cls,
                                              float* __restrict__ outF) {
  int m = blockIdx.x, c = threadIdx.x * 4;
  float4 a = {0.f, 0.f, 0.f, 0.f};
  for (int p = 0; p < 8; ++p) {
    float4 v = *(const float4*)(part + (size_t)p * 262144 + m * 1024 + c);
    a.x += v.x; a.y += v.y; a.z += v.z; a.w += v.w;
  }
  if (c >= 1000) return;
  float* drow = outF + (size_t)m * 1000;
  float vals[4] = {a.x, a.y, a.z, a.w};
  if (c + 3 < 1000) {
    *(float4*)(drow + c) = make_float4(vals[0] + b_cls[c], vals[1] + b_cls[c + 1],
                                       vals[2] + b_cls[c + 2], vals[3] + b_cls[c + 3]);
  } else {
    for (int j = 0; j < 4 && c + j < 1000; ++j) drow[c + j] = vals[j] + b_cls[c + j];
  }
}

// ---------- launch ----------
extern "C" void kernel_launch(void* const* d_in, const int* in_sizes, int n_in,
                              void* d_out, int out_size, void* d_ws, size_t ws_size,
                              hipStream_t stream) {
  const float* x      = (const float*)d_in[0];
  const float* tr     = (const float*)d_in[1];
  const float* hist   = (const float*)d_in[2];
  const float* w_img  = (const float*)d_in[3];
  const float* b_img  = (const float*)d_in[4];
  const float* ln1_s  = (const float*)d_in[5];
  const float* ln1_b  = (const float*)d_in[6];
  const float* w_qkv  = (const float*)d_in[7];
  const float* w_o    = (const float*)d_in[8];
  const float* b_o    = (const float*)d_in[9];
  const float* ln2_s  = (const float*)d_in[10];
  const float* ln2_b  = (const float*)d_in[11];
  const float* w_ff1  = (const float*)d_in[12];
  const float* b_ff1  = (const float*)d_in[13];
  const float* w_ff2  = (const float*)d_in[14];
  const float* b_ff2  = (const float*)d_in[15];
  const float* w_cls  = (const float*)d_in[16];
  const float* b_cls  = (const float*)d_in[17];
  const float* w_tr   = (const float*)d_in[18];
  const float* b_tr   = (const float*)d_in[19];
  float* outF = (float*)d_out;

  char* w = (char*)d_ws;
  auto alloc = [&](size_t bytes) { char* p = w; w += (bytes + 255) & ~(size_t)255; return p; };
  unsigned short* BT_img = (unsigned short*)alloc((size_t)1024 * 4096 * 2);
  unsigned short* BT_qkv = (unsigned short*)alloc((size_t)4 * 1536 * 1024 * 2);
  unsigned short* BT_o   = (unsigned short*)alloc((size_t)4 * 1024 * 512 * 2);
  unsigned short* BT_ff1 = (unsigned short*)alloc((size_t)4 * 1024 * 1024 * 2);
  unsigned short* BT_ff2 = (unsigned short*)alloc((size_t)4 * 1024 * 1024 * 2);
  unsigned short* BT_cls = (unsigned short*)alloc((size_t)1024 * 8192 * 2);
  unsigned short* feats  = (unsigned short*)alloc((size_t)256 * 4096 * 2);
  float*          z      = (float*)alloc((size_t)2048 * 1024 * 4);
  unsigned short* h      = (unsigned short*)alloc((size_t)2048 * 1024 * 2);  // also tl
  unsigned short* obuf   = (unsigned short*)alloc((size_t)2048 * 512 * 2);
  unsigned short* g      = (unsigned short*)alloc((size_t)2048 * 1024 * 2);
  float*          part   = (float*)alloc((size_t)8 * 256 * 1024 * 4);
  if ((size_t)(w - (char*)d_ws) > ws_size) return;

  front1<<<3072, 256, 0, stream>>>(x, tr, hist, w_img, w_qkv, w_o, w_ff1, w_ff2, w_cls,
                                   BT_img, BT_qkv, BT_o, BT_ff1, BT_ff2, BT_cls, feats, z);
  k_img<<<6400, 256, 0, stream>>>(feats, BT_img, part,
                                  w_img, w_qkv, w_o, w_ff1, w_ff2, w_cls,
                                  BT_img, BT_qkv, BT_o, BT_ff1, BT_ff2, BT_cls);
  imgred_ln<<<256, 256, 0, stream>>>(part, b_img, z, ln1_s, ln1_b, h);

  for (int i = 0; i < 4; ++i) {
    const unsigned short* Wq = BT_qkv + (size_t)i * 1536 * 1024;
    const unsigned short* Wo = BT_o   + (size_t)i * 1024 * 512;
    const unsigned short* W1 = BT_ff1 + (size_t)i * 1024 * 1024;
    const unsigned short* W2 = BT_ff2 + (size_t)i * 1024 * 1024;
    if (i > 0)
      ln_kernel<<<512, 256, 0, stream>>>(z, ln1_s + i * 1024, ln1_b + i * 1024, h);
    qkvattn<<<dim3(8, 16), 256, 0, stream>>>(h, Wq, obuf);
    gemm_k<64, 0, 0, true><<<dim3(16, 16), 256, 0, stream>>>(
        obuf, 512, Wo, 512, 512, b_o + i * 1024, z, z, nullptr, 1024, 1024);
    ln_kernel<<<512, 256, 0, stream>>>(z, ln2_s + i * 1024, ln2_b + i * 1024, h);
    gemm_k<64, 1, 1, false><<<dim3(16, 16), 256, 0, stream>>>(
        h, 1024, W1, 1024, 1024, b_ff1 + i * 1024, nullptr, nullptr, g, 1024, 1024);
    if (i < 3) {
      gemm_k<64, 0, 0, true><<<dim3(16, 16), 256, 0, stream>>>(
          g, 1024, W2, 1024, 1024, b_ff2 + i * 1024, z, z, nullptr, 1024, 1024);
    } else {
      gemm_k<64, 0, 2, true><<<dim3(16, 16), 256, 0, stream>>>(
          g, 1024, W2, 1024, 1024, b_ff2 + i * 1024, z, z, h, 1024, 1024);
    }
  }

  k_cls<<<512, 256, 0, stream>>>(h, BT_cls, part, z, w_tr, b_tr, outF);
  clsred<<<256, 256, 0, stream>>>(part, b_cls, outF);
}